// Round 6
// baseline (14940.773 us; speedup 1.0000x reference)
//
#include <hip/hip_runtime.h>

#define DEV __device__ __forceinline__

using bf16x8 = __attribute__((ext_vector_type(8))) short;
using u16x4  = __attribute__((ext_vector_type(4))) unsigned short;
using f32x4  = __attribute__((ext_vector_type(4))) float;

constexpr int B_ = 64, S_ = 512, V_ = 32000, E_ = 512, H_ = 1024, C_ = 1024;
constexpr int NWG = 128;   // scan workgroups (each owns JS columns of H)
constexpr int JS  = 8;

// ---------------- workspace layout (bytes) ----------------
constexpr size_t OFF_FH    = 0;                                   // 128 u32 h-ready flags (count to 4(t+1))
constexpr size_t OFF_FR    = 512;                                 // 128 u32 rh-ready flags
constexpr size_t OFF_BIASG = 1024;                                // 3072 f32
constexpr size_t OFF_BCOMB = OFF_BIASG + 3072*4;                  // 1024 f32
constexpr size_t OFF_HB    = OFF_BCOMB + 1024*4;                  // hF frag-layout bf16 [64][1024]
constexpr size_t OFF_RHB   = OFF_HB + (size_t)B_*H_*2;            // rhF frag-layout bf16
constexpr size_t OFF_WCOMB = OFF_RHB + (size_t)B_*H_*2;           // [1024][1024] bf16
constexpr size_t OFF_WXALL = OFF_WCOMB + (size_t)C_*H_*2;         // [3072][512] bf16
constexpr size_t OFF_WZRF  = OFF_WXALL + (size_t)3072*512*2;      // stage1 frags 128*32KB
constexpr size_t OFF_WUF   = OFF_WZRF + (size_t)NWG*32768;        // stage2 packed frags 128*16KB
constexpr size_t OFF_EMB   = OFF_WUF + (size_t)NWG*16384;         // embed bf16 [32000][512]
constexpr size_t OFF_G     = OFF_EMB + (size_t)V_*E_*2;           // [512][3072][64] bf16
constexpr size_t OFF_HS    = OFF_G + (size_t)S_*B_*3072*2;        // [512*64][1024] bf16
constexpr size_t WS_NEED   = OFF_HS + (size_t)S_*B_*H_*2;         // ~299 MiB

DEV unsigned short f2bf(float f){
  unsigned int x; __builtin_memcpy(&x, &f, 4);
  x += 0x7fffu + ((x>>16)&1u);
  return (unsigned short)(x>>16);
}
DEV float bf2f(unsigned short u){
  unsigned int x = ((unsigned int)u)<<16; float f; __builtin_memcpy(&f,&x,4); return f;
}

// coherent (MALL) 16B load/store + plain 8B load, all volatile asm so the
// hand-counted vmcnt() regions see exactly our VMEM ops.
DEV int4 ld16_coh(const char* p){
  int4 r;
  asm volatile("global_load_dwordx4 %0, %1, off sc0 sc1" : "=v"(r) : "v"(p) : "memory");
  return r;
}
DEV void st16_coh(char* p, bf16x8 v){
  asm volatile("global_store_dwordx4 %0, %1, off sc0 sc1" :: "v"(p), "v"(v) : "memory");
}
DEV uint2 ld8_plain(const char* p){
  uint2 r;
  asm volatile("global_load_dwordx2 %0, %1, off" : "=v"(r) : "v"(p) : "memory");
  return r;
}

#define WAITVM(N) do{ asm volatile("s_waitcnt vmcnt(" #N ")" ::: "memory"); \
                      __builtin_amdgcn_sched_barrier(0); }while(0)
#define WAITLGKM() do{ asm volatile("s_waitcnt lgkmcnt(0)" ::: "memory"); \
                       __builtin_amdgcn_sched_barrier(0); }while(0)

// ---------------- prep kernels ----------------
__global__ void k_cvt_embed(const float* __restrict__ src, unsigned short* __restrict__ dst){
  for (int i = blockIdx.x*blockDim.x + threadIdx.x; i < V_*E_; i += gridDim.x*blockDim.x)
    dst[i] = f2bf(src[i]);
}

__global__ void k_build_wx(const float* __restrict__ Wzx, const float* __restrict__ Wrx,
                           const float* __restrict__ Wux, unsigned short* __restrict__ out){
  for (int i = blockIdx.x*blockDim.x + threadIdx.x; i < 3072*512; i += gridDim.x*blockDim.x){
    int n = i>>9, k = i&511;
    int g = n>>10, r = n&1023;
    const float* W = (g==0) ? Wzx : (g==1) ? Wrx : Wux;
    out[i] = f2bf(W[(size_t)r*512 + k]);
  }
}

__global__ void k_biasg(const float* bzh, const float* bzx, const float* brh, const float* brx,
                        const float* buh, const float* bux, float* __restrict__ out){
  for (int i = blockIdx.x*blockDim.x + threadIdx.x; i < 3072; i += gridDim.x*blockDim.x){
    int g = i>>10, r = i&1023;
    float v = (g==0) ? (bzh[r]+bzx[r]) : (g==1) ? (brh[r]+brx[r]) : (buh[r]+bux[r]);
    out[i] = v;
  }
}

// stage1 B-frags: frag[((wg*32+ck)*64+l)*8+e] = W[row][k], col=l&15 (z:0-7 Wzh, r:8-15 Wrh)
__global__ void k_frag(const float* __restrict__ Wa, const float* __restrict__ Wb,
                       unsigned short* __restrict__ out){
  for (int i = blockIdx.x*blockDim.x + threadIdx.x; i < NWG*32*64*8; i += gridDim.x*blockDim.x){
    int e  = i & 7;
    int l  = (i>>3) & 63;
    int ck = (i>>9) & 31;
    int wg = i>>14;
    int j  = l & 15;
    int k  = ck*32 + ((l>>4)<<3) + e;
    int row = wg*JS + (j&7);
    float v = (j < 8) ? Wa[(size_t)row*H_ + k] : Wb[(size_t)row*H_ + k];
    out[i] = f2bf(v);
  }
}

// stage2 packed frags: out[((wg*32+ck)*32+p)*8+e], p=h8*8+nn -> Wuh[wg*8+nn][ck*32+h8*8+e]
__global__ void k_frag2(const float* __restrict__ Wuh, unsigned short* __restrict__ out){
  for (int i = blockIdx.x*blockDim.x + threadIdx.x; i < NWG*32*32*8; i += gridDim.x*blockDim.x){
    int e=i&7, p=(i>>3)&31, ck=(i>>8)&31, wg=i>>13;
    int nn=p&7, h8=p>>3;
    out[i] = f2bf(Wuh[(size_t)(wg*8+nn)*H_ + ck*32 + h8*8 + e]);
  }
}

// Wcomb[c][h] = sum_x Wc[c][x] * Wxh[x][h]
__global__ __launch_bounds__(256) void k_wcomb(const float* __restrict__ Wc,
                                               const float* __restrict__ Wxh,
                                               unsigned short* __restrict__ Wcomb){
  __shared__ float wc[16][512];
  const int c0 = blockIdx.x*16;
  const int tid = threadIdx.x;
  for (int q = tid; q < 16*512; q += 256)
    wc[q>>9][q&511] = Wc[(size_t)(c0 + (q>>9))*512 + (q&511)];
  __syncthreads();
  const int h4 = tid*4;
  f32x4 acc[16];
  #pragma unroll
  for (int ci=0; ci<16; ++ci) acc[ci] = (f32x4){0.f,0.f,0.f,0.f};
  for (int x=0; x<512; ++x){
    f32x4 wv = *(const f32x4*)(Wxh + (size_t)x*H_ + h4);
    #pragma unroll
    for (int ci=0; ci<16; ++ci) acc[ci] += wc[ci][x] * wv;
  }
  #pragma unroll
  for (int ci=0; ci<16; ++ci)
    #pragma unroll
    for (int e=0; e<4; ++e)
      Wcomb[(size_t)(c0+ci)*H_ + h4 + e] = f2bf(acc[ci][e]);
}

__global__ void k_bcomb(const float* __restrict__ Wc, const float* __restrict__ bxh,
                        const float* __restrict__ bc, float* __restrict__ out){
  int c = blockIdx.x*blockDim.x + threadIdx.x;
  if (c >= C_) return;
  float s = bc[c];
  for (int x=0; x<512; ++x) s += Wc[(size_t)c*512 + x]*bxh[x];
  out[c] = s;
}

// h0 -> fragment layout
__global__ void k_hinit(const float* __restrict__ h0, unsigned short* __restrict__ hbF){
  int i = blockIdx.x*256 + threadIdx.x;   // 65536 total
  int e=i&7, l=(i>>3)&63, ck=(i>>9)&31, w=i>>14;
  hbF[i] = f2bf(h0[(size_t)(w*16+(l&15))*H_ + ck*32 + ((l>>4)<<3) + e]);
}

// ---------------- tiled bf16 MFMA GEMM (C = A @ Bw^T + bias) ----------------
// MODE 1: f32 out scattered to [b][t][C]; MODE 2: bf16 out to G layout [t][gcol][64b]
template<bool GATHER, int MODE>
__global__ __launch_bounds__(256) void gemm_bt(
  const unsigned short* __restrict__ Asrc, const int* __restrict__ Xidx,
  const unsigned short* __restrict__ embB,
  const unsigned short* __restrict__ Bw, const float* __restrict__ bias,
  void* __restrict__ Cout, int K, int KT, int NTN, int ldc)
{
  __shared__ unsigned short ldsA[128*64];
  __shared__ unsigned short ldsB[128*64];
  const int bid = blockIdx.x;
  const int tm = bid / NTN, tn = bid % NTN;
  const int m0 = tm*128, n0 = tn*128;
  const int tid = threadIdx.x, wave = tid>>6, lane = tid&63;
  const int wm = (wave&1)*64, wn = (wave>>1)*64;

  const char* srcA[4]; const char* srcB[4];
  int rr[4], cc[4];
  #pragma unroll
  for (int s=0; s<4; ++s){
    int L = s*4096 + tid*16;
    int r = L>>7, cb = L&127;
    rr[s]=r; cc[s]=cb;
    if constexpr (GATHER){
      int m = m0 + r; int tt = m>>6, bb = m&63;
      srcA[s] = (const char*)(embB + (size_t)Xidx[bb*S_ + tt]*(size_t)K);
    } else {
      srcA[s] = (const char*)(Asrc + (size_t)(m0+r)*(size_t)K);
    }
    srcB[s] = (const char*)(Bw + (size_t)(n0+r)*(size_t)K);
  }

  f32x4 acc[4][4];
  #pragma unroll
  for (int a=0;a<4;a++)
    #pragma unroll
    for (int b=0;b<4;b++) acc[a][b] = (f32x4){0.f,0.f,0.f,0.f};

  int4 ra[4], rb[4];
  auto loadRegs = [&](int kt){
    #pragma unroll
    for (int s=0;s<4;s++){
      ra[s] = *(const int4*)(srcA[s] + (size_t)kt*128 + cc[s]);
      rb[s] = *(const int4*)(srcB[s] + (size_t)kt*128 + cc[s]);
    }
  };
  auto writeLDS = [&](){
    #pragma unroll
    for (int s=0;s<4;s++){
      int off = (rr[s]<<7) + (cc[s] ^ ((rr[s]&7)<<4));
      *(int4*)((char*)ldsA + off) = ra[s];
      *(int4*)((char*)ldsB + off) = rb[s];
    }
  };

  loadRegs(0);
  for (int kt=0; kt<KT; ++kt){
    __syncthreads();
    writeLDS();
    if (kt+1 < KT) loadRegs(kt+1);
    __syncthreads();
    #pragma unroll
    for (int ck=0; ck<2; ++ck){
      bf16x8 af[4], bfr[4];
      #pragma unroll
      for (int q=0;q<4;q++){
        int ar = wm + q*16 + (lane&15);
        int ao = (ar<<7) + (((ck<<6) + ((lane>>4)<<4)) ^ ((ar&7)<<4));
        af[q] = *(const bf16x8*)((const char*)ldsA + ao);
        int br = wn + q*16 + (lane&15);
        int bo = (br<<7) + (((ck<<6) + ((lane>>4)<<4)) ^ ((br&7)<<4));
        bfr[q] = *(const bf16x8*)((const char*)ldsB + bo);
      }
      #pragma unroll
      for (int mi=0;mi<4;mi++)
        #pragma unroll
        for (int ni=0;ni<4;ni++)
          acc[mi][ni] = __builtin_amdgcn_mfma_f32_16x16x32_bf16(af[mi], bfr[ni], acc[mi][ni], 0,0,0);
    }
  }

  #pragma unroll
  for (int mi=0;mi<4;mi++){
    #pragma unroll
    for (int ni=0;ni<4;ni++){
      int gm = m0 + wm + mi*16 + ((lane>>4)<<2);
      int gn = n0 + wn + ni*16 + (lane&15);
      float bv = bias[gn];
      if constexpr (MODE == 1){
        #pragma unroll
        for (int r2=0;r2<4;r2++){
          float v = acc[mi][ni][r2] + bv;
          int m = gm + r2;
          ((float*)Cout)[ (size_t)((m&63)*S_ + (m>>6))*(size_t)ldc + gn ] = v;
        }
      } else {
        int t0 = gm>>6, b0 = gm&63;
        u16x4 pk;
        #pragma unroll
        for (int r2=0;r2<4;r2++) pk[r2] = f2bf(acc[mi][ni][r2] + bv);
        *(u16x4*)((unsigned short*)Cout + ((size_t)t0*3072 + gn)*64 + b0) = pk;
      }
    }
  }
}

// ---------------- persistent GRU scan (per-wave publish, counting flags) ----------------
DEV void pollge(const unsigned int* f, unsigned int p, int lane){
  const unsigned long long* q = (const unsigned long long*)f;
  int guard = 0;
  for(;;){
    unsigned long long v = __hip_atomic_load(&q[lane], __ATOMIC_RELAXED, __HIP_MEMORY_SCOPE_AGENT);
    bool ok = ((unsigned)v >= p) && ((unsigned)(v>>32) >= p);
    if (__all((int)ok)) break;
    if (++guard > (1<<24)) break;   // safety: garbage instead of hang
  }
}

__global__ __launch_bounds__(256,1) void k_scan(const float* __restrict__ h0, char* __restrict__ ws){
  const int wg = blockIdx.x;          // owns H cols [wg*8, wg*8+8)
  const int tid = threadIdx.x;
  const int wave = tid>>6, lane = tid&63;
  const int j0 = wg*JS;
  const int ckw = wg>>2, hiw = wg&3;

  unsigned int* fH = (unsigned int*)(ws + OFF_FH);
  unsigned int* fR = (unsigned int*)(ws + OFF_FR);
  char* hbF  = ws + OFF_HB;
  char* rhbF = ws + OFF_RHB;
  const unsigned short* G = (const unsigned short*)(ws + OFF_G);
  unsigned short* Hs  = (unsigned short*)(ws + OFF_HS);

  __shared__ __align__(16) char lds[32768 + 16384 + 2048];
  char* f1  = lds;
  char* f2p = lds + 32768;
  unsigned short* tAw = (unsigned short*)(lds + 49152 + wave*256);         // [16][8] per-wave rh tile
  unsigned short* tBw = (unsigned short*)(lds + 49152 + 1024 + wave*256);  // [16][8] per-wave h' tile

  { // stage static weight fragments into LDS
    const int4* s1 = (const int4*)(ws + OFF_WZRF + (size_t)wg*32768);
    const int4* s2 = (const int4*)(ws + OFF_WUF  + (size_t)wg*16384);
    #pragma unroll
    for (int i=0;i<8;i++) ((int4*)f1)[tid + i*256] = s1[tid + i*256];
    #pragma unroll
    for (int i=0;i<4;i++) ((int4*)f2p)[tid + i*256] = s2[tid + i*256];
  }
  __syncthreads();   // only barrier in the kernel

  const int n  = lane & 15;
  const int c  = n & 7;
  const bool isZ = (n < 8);
  const int hi2 = lane>>4;
  const int rbase = (wave<<4) + (hi2<<2);
  const int gcol = ((n>>3)<<10) + j0 + c;   // z col (n<8) / r col (n>=8)
  const int col2 = 2048 + j0 + c;           // u col

  float h_own[4];
  #pragma unroll
  for (int r2=0;r2<4;r2++)
    h_own[r2] = isZ ? h0[(size_t)(rbase+r2)*H_ + j0 + c] : 0.f;

  const char* myHb  = hbF  + ((size_t)wave<<15);   // wave's 32KB row-group
  const char* myRhb = rhbF + ((size_t)wave<<15);
  char* pubR = rhbF + ((size_t)wave<<15) + ((size_t)ckw<<10) + (hiw<<8);
  char* pubH = hbF  + ((size_t)wave<<15) + ((size_t)ckw<<10) + (hiw<<8);

#define LOAD8(buf, base, g0) { _Pragma("unroll") \
  for (int i=0;i<8;i++) buf[i] = ld16_coh((base) + ((((g0)*8+i)*64+lane)<<4)); }
#define MFMA8_1(buf, g0) { _Pragma("unroll") \
  for (int i=0;i<8;i++){ int ck=(g0)*8+i; \
    bf16x8 bv = *(const bf16x8*)(f1 + ((ck*64+lane)<<4)); \
    bf16x8 av = __builtin_bit_cast(bf16x8, buf[i]); \
    accv[i&3] = __builtin_amdgcn_mfma_f32_16x16x32_bf16(av,bv,accv[i&3],0,0,0);} }
#define MFMA8_2(buf, g0) { _Pragma("unroll") \
  for (int i=0;i<8;i++){ int ck=(g0)*8+i; \
    bf16x8 bv = *(const bf16x8*)(f2p + ((ck*32 + hi2*8 + c)<<4)); \
    bf16x8 av = __builtin_bit_cast(bf16x8, buf[i]); \
    accv[i&3] = __builtin_amdgcn_mfma_f32_16x16x32_bf16(av,bv,accv[i&3],0,0,0);} }

  for (int t=0; t<S_; ++t){
    // G prefetch (plain cached, coalesced 8B/lane); latency hides under poll
    uint2 gv1 = ld8_plain((const char*)(G + ((size_t)t*3072 + gcol)*64 + rbase));
    uint2 gv2 = ld8_plain((const char*)(G + ((size_t)t*3072 + col2)*64 + rbase));

    if (t > 0) pollge(fH, 4u*(unsigned)t, lane);

    // -------- stage 1: z,r = sigmoid(h@Wzr^T + G) --------
    f32x4 accv[4];
    #pragma unroll
    for (int a=0;a<4;a++) accv[a] = (f32x4){0,0,0,0};
    {
      int4 b0[8], b1[8], b2[8], b3[8];
      LOAD8(b0, myHb, 0); LOAD8(b1, myHb, 1); LOAD8(b2, myHb, 2); LOAD8(b3, myHb, 3);
      WAITVM(24); MFMA8_1(b0, 0);
      WAITVM(16); MFMA8_1(b1, 1);
      WAITVM(8);  MFMA8_1(b2, 2);
      WAITVM(0);  MFMA8_1(b3, 3);
    }
    f32x4 accs = (accv[0]+accv[1]) + (accv[2]+accv[3]);

    float zval[4];
    {
      unsigned short gu[4] = {(unsigned short)(gv1.x&0xffffu),(unsigned short)(gv1.x>>16),
                              (unsigned short)(gv1.y&0xffffu),(unsigned short)(gv1.y>>16)};
      #pragma unroll
      for (int r2=0;r2<4;r2++){
        float pre = accs[r2] + bf2f(gu[r2]);
        float sv = 1.f/(1.f + __expf(-pre));
        float hc = __shfl(h_own[r2], (lane & 48) | c, 64);
        zval[r2] = sv;
        if (!isZ) tAw[(hi2*4 + r2)*8 + c] = f2bf(sv*hc);
      }
    }
    WAITLGKM();                     // same-wave LDS RAW
    if (lane < 16){
      bf16x8 v = *(const bf16x8*)(tAw + lane*8);   // row lane, 8 cols
      st16_coh(pubR + (lane<<4), v);
    }
    WAITVM(0);                      // store-ack before flag
    if (lane == 0)
      __hip_atomic_fetch_add(&fR[wg], 1u, __ATOMIC_RELAXED, __HIP_MEMORY_SCOPE_AGENT);
    pollge(fR, 4u*(unsigned)(t+1), lane);

    // -------- stage 2: u = tanh((r*h)@Wu^T + G), h' = h + z*(u-h) --------
    #pragma unroll
    for (int a=0;a<4;a++) accv[a] = (f32x4){0,0,0,0};
    {
      int4 b0[8], b1[8], b2[8], b3[8];
      LOAD8(b0, myRhb, 0); LOAD8(b1, myRhb, 1); LOAD8(b2, myRhb, 2); LOAD8(b3, myRhb, 3);
      WAITVM(24); MFMA8_2(b0, 0);
      WAITVM(16); MFMA8_2(b1, 1);
      WAITVM(8);  MFMA8_2(b2, 2);
      WAITVM(0);  MFMA8_2(b3, 3);
    }
    f32x4 acc2 = (accv[0]+accv[1]) + (accv[2]+accv[3]);

    if (isZ){
      unsigned short gu[4] = {(unsigned short)(gv2.x&0xffffu),(unsigned short)(gv2.x>>16),
                              (unsigned short)(gv2.y&0xffffu),(unsigned short)(gv2.y>>16)};
      #pragma unroll
      for (int r2=0;r2<4;r2++){
        float up = acc2[r2] + bf2f(gu[r2]);
        float e  = __expf(-2.f*up);
        float u  = (1.f - e)/(1.f + e);
        float hn = h_own[r2] + zval[r2]*(u - h_own[r2]);
        h_own[r2] = hn;
        tBw[(hi2*4 + r2)*8 + c] = f2bf(hn);
      }
    }
    WAITLGKM();
    if (lane < 16){
      bf16x8 v = *(const bf16x8*)(tBw + lane*8);
      st16_coh(pubH + (lane<<4), v);
      *(bf16x8*)(Hs + (size_t)((t<<6) + (wave<<4) + lane)*H_ + j0) = v;  // history, plain (L2 ack)
    }
    WAITVM(0);
    if (lane == 0)
      __hip_atomic_fetch_add(&fH[wg], 1u, __ATOMIC_RELAXED, __HIP_MEMORY_SCOPE_AGENT);
  }
#undef LOAD8
#undef MFMA8_1
#undef MFMA8_2
}

// ---------------- launch ----------------
extern "C" void kernel_launch(void* const* d_in, const int* in_sizes, int n_in,
                              void* d_out, int out_size, void* d_ws, size_t ws_size,
                              hipStream_t stream)
{
  const int*   X    = (const int*)  d_in[0];
  const float* h0   = (const float*)d_in[1];
  const float* emb  = (const float*)d_in[2];
  const float* Wzh  = (const float*)d_in[3];
  const float* bzh  = (const float*)d_in[4];
  const float* Wzx  = (const float*)d_in[5];
  const float* bzx  = (const float*)d_in[6];
  const float* Wrh  = (const float*)d_in[7];
  const float* brh  = (const float*)d_in[8];
  const float* Wrx  = (const float*)d_in[9];
  const float* brx  = (const float*)d_in[10];
  const float* Wuh  = (const float*)d_in[11];
  const float* buh  = (const float*)d_in[12];
  const float* Wux  = (const float*)d_in[13];
  const float* bux  = (const float*)d_in[14];
  const float* Wxh  = (const float*)d_in[15];
  const float* bxh  = (const float*)d_in[16];
  const float* Wc   = (const float*)d_in[17];
  const float* bc   = (const float*)d_in[18];
  (void)in_sizes; (void)n_in;

  char* ws = (char*)d_ws;
  if (ws_size < WS_NEED){
    hipMemsetAsync(d_out, 0, (size_t)out_size*4, stream);  // visible failure
    return;
  }

  hipMemsetAsync(ws + OFF_FH, 0, 1024, stream);   // fH + fR

  k_cvt_embed<<<4096, 256, 0, stream>>>(emb, (unsigned short*)(ws + OFF_EMB));
  k_build_wx <<<1536, 256, 0, stream>>>(Wzx, Wrx, Wux, (unsigned short*)(ws + OFF_WXALL));
  k_biasg    <<<12,   256, 0, stream>>>(bzh, bzx, brh, brx, buh, bux, (float*)(ws + OFF_BIASG));
  k_frag     <<<2048, 256, 0, stream>>>(Wzh, Wrh, (unsigned short*)(ws + OFF_WZRF));
  k_frag2    <<<1024, 256, 0, stream>>>(Wuh,      (unsigned short*)(ws + OFF_WUF));
  k_wcomb    <<<64,   256, 0, stream>>>(Wc, Wxh, (unsigned short*)(ws + OFF_WCOMB));
  k_bcomb    <<<4,    256, 0, stream>>>(Wc, bxh, bc, (float*)(ws + OFF_BCOMB));
  k_hinit    <<<256,  256, 0, stream>>>(h0, (unsigned short*)(ws + OFF_HB));

  // G = gather(embed) @ WxAll^T + bias -> layout [t][gcol][64b] bf16
  gemm_bt<true,2><<<6144, 256, 0, stream>>>(
      nullptr, X, (const unsigned short*)(ws + OFF_EMB),
      (const unsigned short*)(ws + OFF_WXALL), (const float*)(ws + OFF_BIASG),
      (void*)(ws + OFF_G), 512, 8, 24, 3072);

  k_scan<<<NWG, 256, 0, stream>>>(h0, ws);

  // out[b,t,c] = Hs @ Wcomb^T + bcomb (scatter rows t*64+b -> b*512+t)
  gemm_bt<false,1><<<2048, 256, 0, stream>>>(
      (const unsigned short*)(ws + OFF_HS), nullptr, nullptr,
      (const unsigned short*)(ws + OFF_WCOMB), (const float*)(ws + OFF_BCOMB),
      d_out, 1024, 16, 8, 1024);
}

// Round 7
// 7691.809 us; speedup vs baseline: 1.9424x; 1.9424x over previous
//
#include <hip/hip_runtime.h>

#define DEV __device__ __forceinline__

using bf16x8 = __attribute__((ext_vector_type(8))) short;
using u16x4  = __attribute__((ext_vector_type(4))) unsigned short;
using f32x4  = __attribute__((ext_vector_type(4))) float;

constexpr int B_ = 64, S_ = 512, V_ = 32000, E_ = 512, H_ = 1024, C_ = 1024;
constexpr int NWG = 64;    // scan workgroups (each owns JS columns of H)
constexpr int JS  = 16;

// ---------------- workspace layout (bytes) ----------------
constexpr size_t OFF_FH    = 0;                                   // 256 u32 flags [wg][bg]
constexpr size_t OFF_FR    = 1024;                                // 256 u32 flags
constexpr size_t OFF_BIASG = 2048;                                // 3072 f32
constexpr size_t OFF_BCOMB = OFF_BIASG + 3072*4;                  // 1024 f32
constexpr size_t OFF_HB    = OFF_BCOMB + 1024*4;                  // h frag [4 bg][32KB]
constexpr size_t OFF_RHB   = OFF_HB + 131072;                     // rh frag [4 bg][32KB]
constexpr size_t OFF_WCOMB = OFF_RHB + 131072;                    // [1024][1024] bf16
constexpr size_t OFF_WXALL = OFF_WCOMB + (size_t)C_*H_*2;         // [3072][512] bf16
constexpr size_t OFF_WZF   = OFF_WXALL + (size_t)3072*512*2;      // z frags 64*32KB
constexpr size_t OFF_WRF   = OFF_WZF + (size_t)NWG*32768;         // r frags 64*32KB
constexpr size_t OFF_WUF   = OFF_WRF + (size_t)NWG*32768;         // u frags 64*32KB
constexpr size_t OFF_EMB   = OFF_WUF + (size_t)NWG*32768;         // embed bf16 [32000][512]
constexpr size_t OFF_G     = OFF_EMB + (size_t)V_*E_*2;           // [512][3072][64] bf16
constexpr size_t OFF_HS    = OFF_G + (size_t)S_*B_*3072*2;        // [512*64][1024] bf16
constexpr size_t WS_NEED   = OFF_HS + (size_t)S_*B_*H_*2;         // ~299 MiB

DEV unsigned short f2bf(float f){
  unsigned int x; __builtin_memcpy(&x, &f, 4);
  x += 0x7fffu + ((x>>16)&1u);
  return (unsigned short)(x>>16);
}
DEV float bf2f(unsigned short u){
  unsigned int x = ((unsigned int)u)<<16; float f; __builtin_memcpy(&f,&x,4); return f;
}

// coherent (MALL) 16B load/store + plain 8B load, all volatile asm so the
// hand-counted vmcnt() regions see exactly our VMEM ops.
DEV int4 ld16_coh(const char* p){
  int4 r;
  asm volatile("global_load_dwordx4 %0, %1, off sc0 sc1" : "=v"(r) : "v"(p) : "memory");
  return r;
}
DEV void st16_coh(char* p, bf16x8 v){
  asm volatile("global_store_dwordx4 %0, %1, off sc0 sc1" :: "v"(p), "v"(v) : "memory");
}
DEV uint2 ld8_plain(const char* p){
  uint2 r;
  asm volatile("global_load_dwordx2 %0, %1, off" : "=v"(r) : "v"(p) : "memory");
  return r;
}

#define WAITVM(N) do{ asm volatile("s_waitcnt vmcnt(" #N ")" ::: "memory"); \
                      __builtin_amdgcn_sched_barrier(0); }while(0)
#define WAITLGKM() do{ asm volatile("s_waitcnt lgkmcnt(0)" ::: "memory"); \
                       __builtin_amdgcn_sched_barrier(0); }while(0)

// ---------------- prep kernels ----------------
__global__ void k_cvt_embed(const float* __restrict__ src, unsigned short* __restrict__ dst){
  for (int i = blockIdx.x*blockDim.x + threadIdx.x; i < V_*E_; i += gridDim.x*blockDim.x)
    dst[i] = f2bf(src[i]);
}

__global__ void k_build_wx(const float* __restrict__ Wzx, const float* __restrict__ Wrx,
                           const float* __restrict__ Wux, unsigned short* __restrict__ out){
  for (int i = blockIdx.x*blockDim.x + threadIdx.x; i < 3072*512; i += gridDim.x*blockDim.x){
    int n = i>>9, k = i&511;
    int g = n>>10, r = n&1023;
    const float* W = (g==0) ? Wzx : (g==1) ? Wrx : Wux;
    out[i] = f2bf(W[(size_t)r*512 + k]);
  }
}

__global__ void k_biasg(const float* bzh, const float* bzx, const float* brh, const float* brx,
                        const float* buh, const float* bux, float* __restrict__ out){
  for (int i = blockIdx.x*blockDim.x + threadIdx.x; i < 3072; i += gridDim.x*blockDim.x){
    int g = i>>10, r = i&1023;
    float v = (g==0) ? (bzh[r]+bzx[r]) : (g==1) ? (brh[r]+brx[r]) : (buh[r]+bux[r]);
    out[i] = v;
  }
}

// B-frags for one weight: out[((g*32+ck)*64+l)*8+e] = W[g*16+(l&15)][ck*32+(l>>4)*8+e]
__global__ void k_fragW(const float* __restrict__ W, unsigned short* __restrict__ out){
  for (int i = blockIdx.x*blockDim.x + threadIdx.x; i < NWG*32*64*8; i += gridDim.x*blockDim.x){
    int e=i&7, l=(i>>3)&63, ck=(i>>9)&31, g=i>>14;
    out[i] = f2bf(W[(size_t)(g*JS+(l&15))*H_ + ck*32 + ((l>>4)<<3) + e]);
  }
}

// Wcomb[c][h] = sum_x Wc[c][x] * Wxh[x][h]
__global__ __launch_bounds__(256) void k_wcomb(const float* __restrict__ Wc,
                                               const float* __restrict__ Wxh,
                                               unsigned short* __restrict__ Wcomb){
  __shared__ float wc[16][512];
  const int c0 = blockIdx.x*16;
  const int tid = threadIdx.x;
  for (int q = tid; q < 16*512; q += 256)
    wc[q>>9][q&511] = Wc[(size_t)(c0 + (q>>9))*512 + (q&511)];
  __syncthreads();
  const int h4 = tid*4;
  f32x4 acc[16];
  #pragma unroll
  for (int ci=0; ci<16; ++ci) acc[ci] = (f32x4){0.f,0.f,0.f,0.f};
  for (int x=0; x<512; ++x){
    f32x4 wv = *(const f32x4*)(Wxh + (size_t)x*H_ + h4);
    #pragma unroll
    for (int ci=0; ci<16; ++ci) acc[ci] += wc[ci][x] * wv;
  }
  #pragma unroll
  for (int ci=0; ci<16; ++ci)
    #pragma unroll
    for (int e=0; e<4; ++e)
      Wcomb[(size_t)(c0+ci)*H_ + h4 + e] = f2bf(acc[ci][e]);
}

__global__ void k_bcomb(const float* __restrict__ Wc, const float* __restrict__ bxh,
                        const float* __restrict__ bc, float* __restrict__ out){
  int c = blockIdx.x*blockDim.x + threadIdx.x;
  if (c >= C_) return;
  float s = bc[c];
  for (int x=0; x<512; ++x) s += Wc[(size_t)c*512 + x]*bxh[x];
  out[c] = s;
}

// h0 -> per-bg fragment layout
__global__ void k_hinit(const float* __restrict__ h0, unsigned short* __restrict__ hbF){
  int i = blockIdx.x*256 + threadIdx.x;   // 65536 total
  int e=i&7, l=(i>>3)&63, ck=(i>>9)&31, q=i>>14;
  hbF[i] = f2bf(h0[(size_t)(q*16+(l&15))*H_ + ck*32 + ((l>>4)<<3) + e]);
}

// ---------------- tiled bf16 MFMA GEMM (C = A @ Bw^T + bias) ----------------
// MODE 1: f32 out scattered to [b][t][C]; MODE 2: bf16 out to G layout [t][gcol][64b]
template<bool GATHER, int MODE>
__global__ __launch_bounds__(256) void gemm_bt(
  const unsigned short* __restrict__ Asrc, const int* __restrict__ Xidx,
  const unsigned short* __restrict__ embB,
  const unsigned short* __restrict__ Bw, const float* __restrict__ bias,
  void* __restrict__ Cout, int K, int KT, int NTN, int ldc)
{
  __shared__ unsigned short ldsA[128*64];
  __shared__ unsigned short ldsB[128*64];
  const int bid = blockIdx.x;
  const int tm = bid / NTN, tn = bid % NTN;
  const int m0 = tm*128, n0 = tn*128;
  const int tid = threadIdx.x, wave = tid>>6, lane = tid&63;
  const int wm = (wave&1)*64, wn = (wave>>1)*64;

  const char* srcA[4]; const char* srcB[4];
  int rr[4], cc[4];
  #pragma unroll
  for (int s=0; s<4; ++s){
    int L = s*4096 + tid*16;
    int r = L>>7, cb = L&127;
    rr[s]=r; cc[s]=cb;
    if constexpr (GATHER){
      int m = m0 + r; int tt = m>>6, bb = m&63;
      srcA[s] = (const char*)(embB + (size_t)Xidx[bb*S_ + tt]*(size_t)K);
    } else {
      srcA[s] = (const char*)(Asrc + (size_t)(m0+r)*(size_t)K);
    }
    srcB[s] = (const char*)(Bw + (size_t)(n0+r)*(size_t)K);
  }

  f32x4 acc[4][4];
  #pragma unroll
  for (int a=0;a<4;a++)
    #pragma unroll
    for (int b=0;b<4;b++) acc[a][b] = (f32x4){0.f,0.f,0.f,0.f};

  int4 ra[4], rb[4];
  auto loadRegs = [&](int kt){
    #pragma unroll
    for (int s=0;s<4;s++){
      ra[s] = *(const int4*)(srcA[s] + (size_t)kt*128 + cc[s]);
      rb[s] = *(const int4*)(srcB[s] + (size_t)kt*128 + cc[s]);
    }
  };
  auto writeLDS = [&](){
    #pragma unroll
    for (int s=0;s<4;s++){
      int off = (rr[s]<<7) + (cc[s] ^ ((rr[s]&7)<<4));
      *(int4*)((char*)ldsA + off) = ra[s];
      *(int4*)((char*)ldsB + off) = rb[s];
    }
  };

  loadRegs(0);
  for (int kt=0; kt<KT; ++kt){
    __syncthreads();
    writeLDS();
    if (kt+1 < KT) loadRegs(kt+1);
    __syncthreads();
    #pragma unroll
    for (int ck=0; ck<2; ++ck){
      bf16x8 af[4], bfr[4];
      #pragma unroll
      for (int q=0;q<4;q++){
        int ar = wm + q*16 + (lane&15);
        int ao = (ar<<7) + (((ck<<6) + ((lane>>4)<<4)) ^ ((ar&7)<<4));
        af[q] = *(const bf16x8*)((const char*)ldsA + ao);
        int br = wn + q*16 + (lane&15);
        int bo = (br<<7) + (((ck<<6) + ((lane>>4)<<4)) ^ ((br&7)<<4));
        bfr[q] = *(const bf16x8*)((const char*)ldsB + bo);
      }
      #pragma unroll
      for (int mi=0;mi<4;mi++)
        #pragma unroll
        for (int ni=0;ni<4;ni++)
          acc[mi][ni] = __builtin_amdgcn_mfma_f32_16x16x32_bf16(af[mi], bfr[ni], acc[mi][ni], 0,0,0);
    }
  }

  #pragma unroll
  for (int mi=0;mi<4;mi++){
    #pragma unroll
    for (int ni=0;ni<4;ni++){
      int gm = m0 + wm + mi*16 + ((lane>>4)<<2);
      int gn = n0 + wn + ni*16 + (lane&15);
      float bv = bias[gn];
      if constexpr (MODE == 1){
        #pragma unroll
        for (int r2=0;r2<4;r2++){
          float v = acc[mi][ni][r2] + bv;
          int m = gm + r2;
          ((float*)Cout)[ (size_t)((m&63)*S_ + (m>>6))*(size_t)ldc + gn ] = v;
        }
      } else {
        int t0 = gm>>6, b0 = gm&63;
        u16x4 pk;
        #pragma unroll
        for (int r2=0;r2<4;r2++) pk[r2] = f2bf(acc[mi][ni][r2] + bv);
        *(u16x4*)((unsigned short*)Cout + ((size_t)t0*3072 + gn)*64 + b0) = pk;
      }
    }
  }
}

// ---------------- persistent GRU scan (64 WG x 16 cols, per-wave flags) ----------------
// wave (wg,bg) polls flags f[wg'*4+bg] for all wg' (64 lanes, one 4B load each)
DEV void pollq(const unsigned int* f, unsigned int p, int lane, int bg){
  const unsigned int* a = f + lane*4 + bg;
  int guard = 0;
  for(;;){
    unsigned int v = __hip_atomic_load(a, __ATOMIC_RELAXED, __HIP_MEMORY_SCOPE_AGENT);
    if (__all((int)(v >= p))) break;
    __builtin_amdgcn_s_sleep(1);
    if (++guard > (1<<24)) break;   // safety: garbage instead of hang
  }
}

__global__ __launch_bounds__(256,1) void k_scan(const float* __restrict__ h0, char* __restrict__ ws){
  const int wg = blockIdx.x;          // owns H cols [wg*16, wg*16+16)
  const int tid = threadIdx.x;
  const int bg = tid>>6, lane = tid&63;   // wave bg owns batch rows [bg*16, bg*16+16)
  const int j0 = wg*JS;
  const int ckw = wg>>1, hw = wg&1;

  unsigned int* fH = (unsigned int*)(ws + OFF_FH);
  unsigned int* fR = (unsigned int*)(ws + OFF_FR);
  const unsigned short* G = (const unsigned short*)(ws + OFF_G);
  unsigned short* Hs  = (unsigned short*)(ws + OFF_HS);

  const char* EXH = ws + OFF_HB  + ((size_t)bg<<15);   // this wave's 32KB h block
  const char* EXR = ws + OFF_RHB + ((size_t)bg<<15);
  char* pubR = ws + OFF_RHB + ((size_t)bg<<15) + (ckw<<10) + (hw<<9);  // + m*16
  char* pubH = ws + OFF_HB  + ((size_t)bg<<15) + (ckw<<10) + (hw<<9);

  extern __shared__ char lds[];       // 102400 B dynamic
  char* fz  = lds;                    // 32KB z-weight frags
  char* frm = lds + 32768;            // 32KB r-weight frags
  char* fum = lds + 65536;            // 32KB u-weight frags
  unsigned short* tA = (unsigned short*)(lds + 98304  + bg*512);   // [16][16] rh tile
  unsigned short* tB = (unsigned short*)(lds + 100352 + bg*512);   // [16][16] h' tile

  { // stage this WG's weight fragments into LDS (once)
    const int4* sz = (const int4*)(ws + OFF_WZF + ((size_t)wg<<15));
    const int4* sr = (const int4*)(ws + OFF_WRF + ((size_t)wg<<15));
    const int4* su = (const int4*)(ws + OFF_WUF + ((size_t)wg<<15));
    #pragma unroll
    for (int i=0;i<8;i++) ((int4*)fz )[tid + i*256] = sz[tid + i*256];
    #pragma unroll
    for (int i=0;i<8;i++) ((int4*)frm)[tid + i*256] = sr[tid + i*256];
    #pragma unroll
    for (int i=0;i<8;i++) ((int4*)fum)[tid + i*256] = su[tid + i*256];
  }
  __syncthreads();   // only barrier in the kernel

  const int c   = lane & 15;              // output col within group
  const int hi2 = lane >> 4;
  const int rbase = (bg<<4) + (hi2<<2);   // global batch row base of D frag
  const int gzc = j0 + c, grc = 1024 + j0 + c, guc = 2048 + j0 + c;

  float h_own[4];
  #pragma unroll
  for (int r2=0;r2<4;r2++)
    h_own[r2] = h0[(size_t)(rbase+r2)*H_ + j0 + c];

#define LOAD32(base) { _Pragma("unroll") \
  for (int i=0;i<32;i++) b[i] = ld16_coh((base) + ((i*64+lane)<<4)); }
#define S1G(g0) { _Pragma("unroll") \
  for (int i=0;i<8;i++){ int ck=(g0)*8+i; \
    bf16x8 av = __builtin_bit_cast(bf16x8, b[ck]); \
    bf16x8 wz = *(const bf16x8*)(fz  + ((ck*64+lane)<<4)); \
    bf16x8 wr = *(const bf16x8*)(frm + ((ck*64+lane)<<4)); \
    if (i&1){ az1=__builtin_amdgcn_mfma_f32_16x16x32_bf16(av,wz,az1,0,0,0); \
              ar1=__builtin_amdgcn_mfma_f32_16x16x32_bf16(av,wr,ar1,0,0,0);} \
    else    { az0=__builtin_amdgcn_mfma_f32_16x16x32_bf16(av,wz,az0,0,0,0); \
              ar0=__builtin_amdgcn_mfma_f32_16x16x32_bf16(av,wr,ar0,0,0,0);} } }
#define S2G(g0) { _Pragma("unroll") \
  for (int i=0;i<8;i++){ int ck=(g0)*8+i; \
    bf16x8 av = __builtin_bit_cast(bf16x8, b[ck]); \
    bf16x8 wu = *(const bf16x8*)(fum + ((ck*64+lane)<<4)); \
    if (i&1) au1=__builtin_amdgcn_mfma_f32_16x16x32_bf16(av,wu,au1,0,0,0); \
    else     au0=__builtin_amdgcn_mfma_f32_16x16x32_bf16(av,wu,au0,0,0,0); } }

  for (int t=0; t<S_; ++t){
    // G prefetch (plain cached, coalesced 8B/lane); drains during poll
    uint2 gv1 = ld8_plain((const char*)(G + ((size_t)t*3072 + gzc)*64 + rbase));
    uint2 gv2 = ld8_plain((const char*)(G + ((size_t)t*3072 + grc)*64 + rbase));
    uint2 gv3 = ld8_plain((const char*)(G + ((size_t)t*3072 + guc)*64 + rbase));

    if (t > 0) pollq(fH, (unsigned)t, lane, bg);

    // -------- stage 1: z,r = sigmoid(h@W^T + G), rh = r*h --------
    f32x4 az0=(f32x4){0,0,0,0}, az1=(f32x4){0,0,0,0};
    f32x4 ar0=(f32x4){0,0,0,0}, ar1=(f32x4){0,0,0,0};
    int4 b[32];
    LOAD32(EXH);
    WAITVM(24); S1G(0);
    WAITVM(16); S1G(1);
    WAITVM(8);  S1G(2);
    WAITVM(0);  S1G(3);
    f32x4 zpre = az0+az1, rpre = ar0+ar1;

    float zval[4];
    {
      unsigned short gz4[4] = {(unsigned short)(gv1.x&0xffffu),(unsigned short)(gv1.x>>16),
                               (unsigned short)(gv1.y&0xffffu),(unsigned short)(gv1.y>>16)};
      unsigned short gr4[4] = {(unsigned short)(gv2.x&0xffffu),(unsigned short)(gv2.x>>16),
                               (unsigned short)(gv2.y&0xffffu),(unsigned short)(gv2.y>>16)};
      #pragma unroll
      for (int r2=0;r2<4;r2++){
        float z = 1.f/(1.f + __expf(-(zpre[r2] + bf2f(gz4[r2]))));
        float r = 1.f/(1.f + __expf(-(rpre[r2] + bf2f(gr4[r2]))));
        zval[r2] = z;
        tA[(hi2*4 + r2)*16 + c] = f2bf(r * h_own[r2]);
      }
    }
    WAITLGKM();                         // same-wave LDS RAW
    if (lane < 32){
      bf16x8 v = *(const bf16x8*)(tA + (lane&15)*16 + ((lane>>4)<<3));
      st16_coh(pubR + (lane<<4), v);
    }
    WAITVM(0);                          // store-ack (and read-drain) before flag
    if (lane == 0)
      __hip_atomic_store(&fR[wg*4+bg], (unsigned)(t+1), __ATOMIC_RELAXED, __HIP_MEMORY_SCOPE_AGENT);
    pollq(fR, (unsigned)(t+1), lane, bg);

    // -------- stage 2: u = tanh(rh@Wu^T + G), h' = h + z*(u-h) --------
    f32x4 au0=(f32x4){0,0,0,0}, au1=(f32x4){0,0,0,0};
    LOAD32(EXR);
    WAITVM(24); S2G(0);
    WAITVM(16); S2G(1);
    WAITVM(8);  S2G(2);
    WAITVM(0);  S2G(3);
    f32x4 upre = au0+au1;

    {
      unsigned short gu4[4] = {(unsigned short)(gv3.x&0xffffu),(unsigned short)(gv3.x>>16),
                               (unsigned short)(gv3.y&0xffffu),(unsigned short)(gv3.y>>16)};
      #pragma unroll
      for (int r2=0;r2<4;r2++){
        float up = upre[r2] + bf2f(gu4[r2]);
        float e  = __expf(-2.f*up);
        float u  = (1.f - e)/(1.f + e);
        float hn = h_own[r2] + zval[r2]*(u - h_own[r2]);
        h_own[r2] = hn;
        tB[(hi2*4 + r2)*16 + c] = f2bf(hn);
      }
    }
    WAITLGKM();
    if (lane < 32){
      bf16x8 v = *(const bf16x8*)(tB + (lane&15)*16 + ((lane>>4)<<3));
      st16_coh(pubH + (lane<<4), v);
      *(bf16x8*)(Hs + (size_t)((t<<6) + (bg<<4) + (lane&15))*H_ + j0 + ((lane>>4)<<3)) = v;
    }
    WAITVM(0);
    if (lane == 0)
      __hip_atomic_store(&fH[wg*4+bg], (unsigned)(t+1), __ATOMIC_RELAXED, __HIP_MEMORY_SCOPE_AGENT);
  }
#undef LOAD32
#undef S1G
#undef S2G
}

// ---------------- launch ----------------
extern "C" void kernel_launch(void* const* d_in, const int* in_sizes, int n_in,
                              void* d_out, int out_size, void* d_ws, size_t ws_size,
                              hipStream_t stream)
{
  const int*   X    = (const int*)  d_in[0];
  const float* h0   = (const float*)d_in[1];
  const float* emb  = (const float*)d_in[2];
  const float* Wzh  = (const float*)d_in[3];
  const float* bzh  = (const float*)d_in[4];
  const float* Wzx  = (const float*)d_in[5];
  const float* bzx  = (const float*)d_in[6];
  const float* Wrh  = (const float*)d_in[7];
  const float* brh  = (const float*)d_in[8];
  const float* Wrx  = (const float*)d_in[9];
  const float* brx  = (const float*)d_in[10];
  const float* Wuh  = (const float*)d_in[11];
  const float* buh  = (const float*)d_in[12];
  const float* Wux  = (const float*)d_in[13];
  const float* bux  = (const float*)d_in[14];
  const float* Wxh  = (const float*)d_in[15];
  const float* bxh  = (const float*)d_in[16];
  const float* Wc   = (const float*)d_in[17];
  const float* bc   = (const float*)d_in[18];
  (void)in_sizes; (void)n_in;

  char* ws = (char*)d_ws;
  if (ws_size < WS_NEED){
    hipMemsetAsync(d_out, 0, (size_t)out_size*4, stream);  // visible failure
    return;
  }

  hipMemsetAsync(ws + OFF_FH, 0, 2048, stream);   // fH + fR

  k_cvt_embed<<<4096, 256, 0, stream>>>(emb, (unsigned short*)(ws + OFF_EMB));
  k_build_wx <<<1536, 256, 0, stream>>>(Wzx, Wrx, Wux, (unsigned short*)(ws + OFF_WXALL));
  k_biasg    <<<12,   256, 0, stream>>>(bzh, bzx, brh, brx, buh, bux, (float*)(ws + OFF_BIASG));
  k_fragW    <<<2048, 256, 0, stream>>>(Wzh, (unsigned short*)(ws + OFF_WZF));
  k_fragW    <<<2048, 256, 0, stream>>>(Wrh, (unsigned short*)(ws + OFF_WRF));
  k_fragW    <<<2048, 256, 0, stream>>>(Wuh, (unsigned short*)(ws + OFF_WUF));
  k_wcomb    <<<64,   256, 0, stream>>>(Wc, Wxh, (unsigned short*)(ws + OFF_WCOMB));
  k_bcomb    <<<4,    256, 0, stream>>>(Wc, bxh, bc, (float*)(ws + OFF_BCOMB));
  k_hinit    <<<256,  256, 0, stream>>>(h0, (unsigned short*)(ws + OFF_HB));

  // G = gather(embed) @ WxAll^T + bias -> layout [t][gcol][64b] bf16
  gemm_bt<true,2><<<6144, 256, 0, stream>>>(
      nullptr, X, (const unsigned short*)(ws + OFF_EMB),
      (const unsigned short*)(ws + OFF_WXALL), (const float*)(ws + OFF_BIASG),
      (void*)(ws + OFF_G), 512, 8, 24, 3072);

  hipFuncSetAttribute((const void*)k_scan, hipFuncAttributeMaxDynamicSharedMemorySize, 102400);
  k_scan<<<NWG, 256, 102400, stream>>>(h0, ws);

  // out[b,t,c] = Hs @ Wcomb^T + bcomb (scatter rows t*64+b -> b*512+t)
  gemm_bt<false,1><<<2048, 256, 0, stream>>>(
      (const unsigned short*)(ws + OFF_HS), nullptr, nullptr,
      (const unsigned short*)(ws + OFF_WCOMB), (const float*)(ws + OFF_BCOMB),
      d_out, 1024, 16, 8, 1024);
}

// Round 10
// 6808.846 us; speedup vs baseline: 2.1943x; 1.1297x over previous
//
#include <hip/hip_runtime.h>

#define DEV __device__ __forceinline__

using bf16x8 = __attribute__((ext_vector_type(8))) short;
using u16x4  = __attribute__((ext_vector_type(4))) unsigned short;
using f32x4  = __attribute__((ext_vector_type(4))) float;

constexpr int B_ = 64, S_ = 512, V_ = 32000, E_ = 512, H_ = 1024, C_ = 1024;
constexpr int NWG = 64;    // scan workgroups (each owns JS columns of H)
constexpr int JS  = 16;

// ---------------- workspace layout (bytes) ----------------
constexpr size_t OFF_FH    = 0;                                   // 256 u32 flags [wg][bg]
constexpr size_t OFF_FR    = 1024;                                // 256 u32 flags
constexpr size_t OFF_BIASG = 2048;                                // 3072 f32
constexpr size_t OFF_BCOMB = OFF_BIASG + 3072*4;                  // 1024 f32
constexpr size_t OFF_HB    = OFF_BCOMB + 1024*4;                  // h frag [4 bg][32KB]
constexpr size_t OFF_RHB   = OFF_HB + 131072;                     // rh frag [4 bg][32KB]
constexpr size_t OFF_WCOMB = OFF_RHB + 131072;                    // [1024][1024] bf16
constexpr size_t OFF_WXALL = OFF_WCOMB + (size_t)C_*H_*2;         // [3072][512] bf16
constexpr size_t OFF_WZF   = OFF_WXALL + (size_t)3072*512*2;      // z frags 64*32KB
constexpr size_t OFF_WRF   = OFF_WZF + (size_t)NWG*32768;         // r frags
constexpr size_t OFF_WUF   = OFF_WRF + (size_t)NWG*32768;         // u frags
constexpr size_t OFF_EMB   = OFF_WUF + (size_t)NWG*32768;         // embed bf16 [32000][512]
constexpr size_t OFF_G     = OFF_EMB + (size_t)V_*E_*2;           // [512][3072][64] bf16
constexpr size_t OFF_HS    = OFF_G + (size_t)S_*B_*3072*2;        // [512*64][1024] bf16
constexpr size_t WS_NEED   = OFF_HS + (size_t)S_*B_*H_*2;         // ~299 MiB

DEV unsigned short f2bf(float f){
  unsigned int x; __builtin_memcpy(&x, &f, 4);
  x += 0x7fffu + ((x>>16)&1u);
  return (unsigned short)(x>>16);
}
DEV float bf2f(unsigned short u){
  unsigned int x = ((unsigned int)u)<<16; float f; __builtin_memcpy(&f,&x,4); return f;
}

// coherent (MALL) 16B load/store + plain 8B load, all volatile asm so the
// hand-counted vmcnt() regions see exactly our VMEM ops.
DEV int4 ld16_coh(const char* p){
  int4 r;
  asm volatile("global_load_dwordx4 %0, %1, off sc0 sc1" : "=v"(r) : "v"(p) : "memory");
  return r;
}
DEV void st16_coh(char* p, bf16x8 v){
  asm volatile("global_store_dwordx4 %0, %1, off sc0 sc1" :: "v"(p), "v"(v) : "memory");
}
DEV uint2 ld8_plain(const char* p){
  uint2 r;
  asm volatile("global_load_dwordx2 %0, %1, off" : "=v"(r) : "v"(p) : "memory");
  return r;
}

#define WAITVM(N) do{ asm volatile("s_waitcnt vmcnt(" #N ")" ::: "memory"); \
                      __builtin_amdgcn_sched_barrier(0); }while(0)
#define WAITLGKM() do{ asm volatile("s_waitcnt lgkmcnt(0)" ::: "memory"); \
                       __builtin_amdgcn_sched_barrier(0); }while(0)

// ---------------- prep kernels ----------------
__global__ void k_cvt_embed(const float* __restrict__ src, unsigned short* __restrict__ dst){
  for (int i = blockIdx.x*blockDim.x + threadIdx.x; i < V_*E_; i += gridDim.x*blockDim.x)
    dst[i] = f2bf(src[i]);
}

__global__ void k_build_wx(const float* __restrict__ Wzx, const float* __restrict__ Wrx,
                           const float* __restrict__ Wux, unsigned short* __restrict__ out){
  for (int i = blockIdx.x*blockDim.x + threadIdx.x; i < 3072*512; i += gridDim.x*blockDim.x){
    int n = i>>9, k = i&511;
    int g = n>>10, r = n&1023;
    const float* W = (g==0) ? Wzx : (g==1) ? Wrx : Wux;
    out[i] = f2bf(W[(size_t)r*512 + k]);
  }
}

__global__ void k_biasg(const float* bzh, const float* bzx, const float* brh, const float* brx,
                        const float* buh, const float* bux, float* __restrict__ out){
  for (int i = blockIdx.x*blockDim.x + threadIdx.x; i < 3072; i += gridDim.x*blockDim.x){
    int g = i>>10, r = i&1023;
    float v = (g==0) ? (bzh[r]+bzx[r]) : (g==1) ? (brh[r]+brx[r]) : (buh[r]+bux[r]);
    out[i] = v;
  }
}

// B-frags for one weight: out[((g*32+ck)*64+l)*8+e] = W[g*16+(l&15)][ck*32+(l>>4)*8+e]
__global__ void k_fragW(const float* __restrict__ W, unsigned short* __restrict__ out){
  for (int i = blockIdx.x*blockDim.x + threadIdx.x; i < NWG*32*64*8; i += gridDim.x*blockDim.x){
    int e=i&7, l=(i>>3)&63, ck=(i>>9)&31, g=i>>14;
    out[i] = f2bf(W[(size_t)(g*JS+(l&15))*H_ + ck*32 + ((l>>4)<<3) + e]);
  }
}

// Wcomb[c][h] = sum_x Wc[c][x] * Wxh[x][h]
__global__ __launch_bounds__(256) void k_wcomb(const float* __restrict__ Wc,
                                               const float* __restrict__ Wxh,
                                               unsigned short* __restrict__ Wcomb){
  __shared__ float wc[16][512];
  const int c0 = blockIdx.x*16;
  const int tid = threadIdx.x;
  for (int q = tid; q < 16*512; q += 256)
    wc[q>>9][q&511] = Wc[(size_t)(c0 + (q>>9))*512 + (q&511)];
  __syncthreads();
  const int h4 = tid*4;
  f32x4 acc[16];
  #pragma unroll
  for (int ci=0; ci<16; ++ci) acc[ci] = (f32x4){0.f,0.f,0.f,0.f};
  for (int x=0; x<512; ++x){
    f32x4 wv = *(const f32x4*)(Wxh + (size_t)x*H_ + h4);
    #pragma unroll
    for (int ci=0; ci<16; ++ci) acc[ci] += wc[ci][x] * wv;
  }
  #pragma unroll
  for (int ci=0; ci<16; ++ci)
    #pragma unroll
    for (int e=0; e<4; ++e)
      Wcomb[(size_t)(c0+ci)*H_ + h4 + e] = f2bf(acc[ci][e]);
}

__global__ void k_bcomb(const float* __restrict__ Wc, const float* __restrict__ bxh,
                        const float* __restrict__ bc, float* __restrict__ out){
  int c = blockIdx.x*blockDim.x + threadIdx.x;
  if (c >= C_) return;
  float s = bc[c];
  for (int x=0; x<512; ++x) s += Wc[(size_t)c*512 + x]*bxh[x];
  out[c] = s;
}

// h0 -> per-bg fragment layout
__global__ void k_hinit(const float* __restrict__ h0, unsigned short* __restrict__ hbF){
  int i = blockIdx.x*256 + threadIdx.x;   // 65536 total
  int e=i&7, l=(i>>3)&63, ck=(i>>9)&31, q=i>>14;
  hbF[i] = f2bf(h0[(size_t)(q*16+(l&15))*H_ + ck*32 + ((l>>4)<<3) + e]);
}

// ---------------- tiled bf16 MFMA GEMM (C = A @ Bw^T + bias) ----------------
// MODE 1: f32 out scattered to [b][t][C]; MODE 2: bf16 out to G layout [t][gcol][64b]
template<bool GATHER, int MODE>
__global__ __launch_bounds__(256) void gemm_bt(
  const unsigned short* __restrict__ Asrc, const int* __restrict__ Xidx,
  const unsigned short* __restrict__ embB,
  const unsigned short* __restrict__ Bw, const float* __restrict__ bias,
  void* __restrict__ Cout, int K, int KT, int NTN, int ldc)
{
  __shared__ unsigned short ldsA[128*64];
  __shared__ unsigned short ldsB[128*64];
  const int bid = blockIdx.x;
  const int tm = bid / NTN, tn = bid % NTN;
  const int m0 = tm*128, n0 = tn*128;
  const int tid = threadIdx.x, wave = tid>>6, lane = tid&63;
  const int wm = (wave&1)*64, wn = (wave>>1)*64;

  const char* srcA[4]; const char* srcB[4];
  int rr[4], cc[4];
  #pragma unroll
  for (int s=0; s<4; ++s){
    int L = s*4096 + tid*16;
    int r = L>>7, cb = L&127;
    rr[s]=r; cc[s]=cb;
    if constexpr (GATHER){
      int m = m0 + r; int tt = m>>6, bb = m&63;
      srcA[s] = (const char*)(embB + (size_t)Xidx[bb*S_ + tt]*(size_t)K);
    } else {
      srcA[s] = (const char*)(Asrc + (size_t)(m0+r)*(size_t)K);
    }
    srcB[s] = (const char*)(Bw + (size_t)(n0+r)*(size_t)K);
  }

  f32x4 acc[4][4];
  #pragma unroll
  for (int a=0;a<4;a++)
    #pragma unroll
    for (int b=0;b<4;b++) acc[a][b] = (f32x4){0.f,0.f,0.f,0.f};

  int4 ra[4], rb[4];
  auto loadRegs = [&](int kt){
    #pragma unroll
    for (int s=0;s<4;s++){
      ra[s] = *(const int4*)(srcA[s] + (size_t)kt*128 + cc[s]);
      rb[s] = *(const int4*)(srcB[s] + (size_t)kt*128 + cc[s]);
    }
  };
  auto writeLDS = [&](){
    #pragma unroll
    for (int s=0;s<4;s++){
      int off = (rr[s]<<7) + (cc[s] ^ ((rr[s]&7)<<4));
      *(int4*)((char*)ldsA + off) = ra[s];
      *(int4*)((char*)ldsB + off) = rb[s];
    }
  };

  loadRegs(0);
  for (int kt=0; kt<KT; ++kt){
    __syncthreads();
    writeLDS();
    if (kt+1 < KT) loadRegs(kt+1);
    __syncthreads();
    #pragma unroll
    for (int ck=0; ck<2; ++ck){
      bf16x8 af[4], bfr[4];
      #pragma unroll
      for (int q=0;q<4;q++){
        int ar = wm + q*16 + (lane&15);
        int ao = (ar<<7) + (((ck<<6) + ((lane>>4)<<4)) ^ ((ar&7)<<4));
        af[q] = *(const bf16x8*)((const char*)ldsA + ao);
        int br = wn + q*16 + (lane&15);
        int bo = (br<<7) + (((ck<<6) + ((lane>>4)<<4)) ^ ((br&7)<<4));
        bfr[q] = *(const bf16x8*)((const char*)ldsB + bo);
      }
      #pragma unroll
      for (int mi=0;mi<4;mi++)
        #pragma unroll
        for (int ni=0;ni<4;ni++)
          acc[mi][ni] = __builtin_amdgcn_mfma_f32_16x16x32_bf16(af[mi], bfr[ni], acc[mi][ni], 0,0,0);
    }
  }

  #pragma unroll
  for (int mi=0;mi<4;mi++){
    #pragma unroll
    for (int ni=0;ni<4;ni++){
      int gm = m0 + wm + mi*16 + ((lane>>4)<<2);
      int gn = n0 + wn + ni*16 + (lane&15);
      float bv = bias[gn];
      if constexpr (MODE == 1){
        #pragma unroll
        for (int r2=0;r2<4;r2++){
          float v = acc[mi][ni][r2] + bv;
          int m = gm + r2;
          ((float*)Cout)[ (size_t)((m&63)*S_ + (m>>6))*(size_t)ldc + gn ] = v;
        }
      } else {
        int t0 = gm>>6, b0 = gm&63;
        u16x4 pk;
        #pragma unroll
        for (int r2=0;r2<4;r2++) pk[r2] = f2bf(acc[mi][ni][r2] + bv);
        *(u16x4*)((unsigned short*)Cout + ((size_t)t0*3072 + gn)*64 + b0) = pk;
      }
    }
  }
}

// ---------------- persistent GRU scan: per-group pipelined flags ----------------
// group g = producer wgs [g*16,(g+1)*16) = frags ck [g*8,(g+1)*8)
DEV void pollgrp(const unsigned int* f, unsigned int p, int lane, int bg, int g){
  const unsigned int* a = f + ((unsigned)(g*16 + (lane&15))*4 + bg);
  int guard = 0;
  for(;;){
    unsigned int v = __hip_atomic_load(a, __ATOMIC_RELAXED, __HIP_MEMORY_SCOPE_AGENT);
    if (__all((int)(v >= p))) break;
    __builtin_amdgcn_s_sleep(1);
    if (++guard > (1<<24)) break;   // safety: garbage instead of hang
  }
}

__global__ __launch_bounds__(256,1) void k_scan(const float* __restrict__ h0, char* __restrict__ ws){
  const int wg = blockIdx.x;          // owns H cols [wg*16, wg*16+16)
  const int tid = threadIdx.x;
  const int bg = tid>>6, lane = tid&63;   // wave bg owns batch rows [bg*16, bg*16+16)
  const int j0 = wg*JS;
  const int ckw = wg>>1, hw = wg&1;

  unsigned int* fH = (unsigned int*)(ws + OFF_FH);
  unsigned int* fR = (unsigned int*)(ws + OFF_FR);
  const unsigned short* G = (const unsigned short*)(ws + OFF_G);
  unsigned short* Hs  = (unsigned short*)(ws + OFF_HS);

  const char* EXH = ws + OFF_HB  + ((size_t)bg<<15);   // this wave's 32KB h block
  const char* EXR = ws + OFF_RHB + ((size_t)bg<<15);
  char* pubR = ws + OFF_RHB + ((size_t)bg<<15) + (ckw<<10) + (hw<<9);
  char* pubH = ws + OFF_HB  + ((size_t)bg<<15) + (ckw<<10) + (hw<<9);

  extern __shared__ char lds[];       // 102400 B dynamic
  char* fz  = lds;                    // 32KB z-weight frags
  char* frm = lds + 32768;            // 32KB r-weight frags
  char* fum = lds + 65536;            // 32KB u-weight frags
  unsigned short* tA = (unsigned short*)(lds + 98304  + bg*512);   // [16][16] rh tile
  unsigned short* tB = (unsigned short*)(lds + 100352 + bg*512);   // [16][16] h' tile

  { // stage this WG's weight fragments into LDS (once)
    const int4* sz = (const int4*)(ws + OFF_WZF + ((size_t)wg<<15));
    const int4* sr = (const int4*)(ws + OFF_WRF + ((size_t)wg<<15));
    const int4* su = (const int4*)(ws + OFF_WUF + ((size_t)wg<<15));
    #pragma unroll
    for (int i=0;i<8;i++) ((int4*)fz )[tid + i*256] = sz[tid + i*256];
    #pragma unroll
    for (int i=0;i<8;i++) ((int4*)frm)[tid + i*256] = sr[tid + i*256];
    #pragma unroll
    for (int i=0;i<8;i++) ((int4*)fum)[tid + i*256] = su[tid + i*256];
  }
  __syncthreads();   // only barrier in the kernel

  const int c   = lane & 15;              // output col within group
  const int hi2 = lane >> 4;
  const int rbase = (bg<<4) + (hi2<<2);   // global batch row base of D frag
  const int gzc = j0 + c, grc = 1024 + j0 + c, guc = 2048 + j0 + c;

  // rotated group order (per-wg) so consumers spread across producer groups
  const int gA=(wg)&3, gB=(wg+1)&3, gC=(wg+2)&3, gD=(wg+3)&3;

  float h_own[4];
  #pragma unroll
  for (int r2=0;r2<4;r2++)
    h_own[r2] = h0[(size_t)(rbase+r2)*H_ + j0 + c];

#define ISSUE8(buf, base, g) { _Pragma("unroll") \
  for (int i=0;i<8;i++) buf[i] = ld16_coh((base) + ((((g)*8+i)*64+lane)<<4)); }
#define CONS1(buf, g) { _Pragma("unroll") \
  for (int i=0;i<8;i++){ int ck=(g)*8+i; \
    bf16x8 av = __builtin_bit_cast(bf16x8, buf[i]); \
    bf16x8 wz = *(const bf16x8*)(fz  + ((ck*64+lane)<<4)); \
    bf16x8 wr = *(const bf16x8*)(frm + ((ck*64+lane)<<4)); \
    if (i&1){ az1=__builtin_amdgcn_mfma_f32_16x16x32_bf16(av,wz,az1,0,0,0); \
              ar1=__builtin_amdgcn_mfma_f32_16x16x32_bf16(av,wr,ar1,0,0,0);} \
    else    { az0=__builtin_amdgcn_mfma_f32_16x16x32_bf16(av,wz,az0,0,0,0); \
              ar0=__builtin_amdgcn_mfma_f32_16x16x32_bf16(av,wr,ar0,0,0,0);} } }
#define CONS2(buf, g) { _Pragma("unroll") \
  for (int i=0;i<8;i++){ int ck=(g)*8+i; \
    bf16x8 av = __builtin_bit_cast(bf16x8, buf[i]); \
    bf16x8 wu = *(const bf16x8*)(fum + ((ck*64+lane)<<4)); \
    if (i&1) au1=__builtin_amdgcn_mfma_f32_16x16x32_bf16(av,wu,au1,0,0,0); \
    else     au0=__builtin_amdgcn_mfma_f32_16x16x32_bf16(av,wu,au0,0,0,0); } }

  for (int t=0; t<S_; ++t){
    // G prefetch (plain cached, coalesced 8B/lane); drains under first poll/wait
    uint2 gv1 = ld8_plain((const char*)(G + ((size_t)t*3072 + gzc)*64 + rbase));
    uint2 gv2 = ld8_plain((const char*)(G + ((size_t)t*3072 + grc)*64 + rbase));
    uint2 gv3 = ld8_plain((const char*)(G + ((size_t)t*3072 + guc)*64 + rbase));

    // -------- stage 1: z,r = sigmoid(h@W^T + G), rh = r*h --------
    f32x4 az0=(f32x4){0,0,0,0}, az1=(f32x4){0,0,0,0};
    f32x4 ar0=(f32x4){0,0,0,0}, ar1=(f32x4){0,0,0,0};
    {
      int4 bA[8], bB[8];
      if (t>0) pollgrp(fH, (unsigned)t, lane, bg, gA);
      ISSUE8(bA, EXH, gA);
      if (t>0) pollgrp(fH, (unsigned)t, lane, bg, gB);
      ISSUE8(bB, EXH, gB);
      WAITVM(8);  CONS1(bA, gA);
      if (t>0) pollgrp(fH, (unsigned)t, lane, bg, gC);
      ISSUE8(bA, EXH, gC);
      WAITVM(8);  CONS1(bB, gB);
      if (t>0) pollgrp(fH, (unsigned)t, lane, bg, gD);
      ISSUE8(bB, EXH, gD);
      WAITVM(8);  CONS1(bA, gC);
      WAITVM(0);  CONS1(bB, gD);
    }
    f32x4 zpre = az0+az1, rpre = ar0+ar1;

    float zval[4];
    {
      unsigned short gz4[4] = {(unsigned short)(gv1.x&0xffffu),(unsigned short)(gv1.x>>16),
                               (unsigned short)(gv1.y&0xffffu),(unsigned short)(gv1.y>>16)};
      unsigned short gr4[4] = {(unsigned short)(gv2.x&0xffffu),(unsigned short)(gv2.x>>16),
                               (unsigned short)(gv2.y&0xffffu),(unsigned short)(gv2.y>>16)};
      #pragma unroll
      for (int r2=0;r2<4;r2++){
        float z = 1.f/(1.f + __expf(-(zpre[r2] + bf2f(gz4[r2]))));
        float r = 1.f/(1.f + __expf(-(rpre[r2] + bf2f(gr4[r2]))));
        zval[r2] = z;
        tA[(hi2*4 + r2)*16 + c] = f2bf(r * h_own[r2]);
      }
    }
    WAITLGKM();                         // same-wave LDS RAW
    if (lane < 32){
      bf16x8 v = *(const bf16x8*)(tA + (lane&15)*16 + ((lane>>4)<<3));
      st16_coh(pubR + (lane<<4), v);
    }
    WAITVM(0);                          // store-ack before flag
    if (lane == 0)
      __hip_atomic_store(&fR[wg*4+bg], (unsigned)(t+1), __ATOMIC_RELAXED, __HIP_MEMORY_SCOPE_AGENT);

    // -------- stage 2: u = tanh(rh@Wu^T + G), h' = h + z*(u-h) --------
    f32x4 au0=(f32x4){0,0,0,0}, au1=(f32x4){0,0,0,0};
    {
      int4 bA[8], bB[8];
      pollgrp(fR, (unsigned)(t+1), lane, bg, gA);
      ISSUE8(bA, EXR, gA);
      pollgrp(fR, (unsigned)(t+1), lane, bg, gB);
      ISSUE8(bB, EXR, gB);
      WAITVM(8);  CONS2(bA, gA);
      pollgrp(fR, (unsigned)(t+1), lane, bg, gC);
      ISSUE8(bA, EXR, gC);
      WAITVM(8);  CONS2(bB, gB);
      pollgrp(fR, (unsigned)(t+1), lane, bg, gD);
      ISSUE8(bB, EXR, gD);
      WAITVM(8);  CONS2(bA, gC);
      WAITVM(0);  CONS2(bB, gD);
    }
    f32x4 upre = au0+au1;

    {
      unsigned short gu4[4] = {(unsigned short)(gv3.x&0xffffu),(unsigned short)(gv3.x>>16),
                               (unsigned short)(gv3.y&0xffffu),(unsigned short)(gv3.y>>16)};
      #pragma unroll
      for (int r2=0;r2<4;r2++){
        float up = upre[r2] + bf2f(gu4[r2]);
        float e  = __expf(-2.f*up);
        float u  = (1.f - e)/(1.f + e);
        float hn = h_own[r2] + zval[r2]*(u - h_own[r2]);
        h_own[r2] = hn;
        tB[(hi2*4 + r2)*16 + c] = f2bf(hn);
      }
    }
    WAITLGKM();
    if (lane < 32){
      bf16x8 v = *(const bf16x8*)(tB + (lane&15)*16 + ((lane>>4)<<3));
      st16_coh(pubH + (lane<<4), v);
      *(bf16x8*)(Hs + (size_t)((t<<6) + (bg<<4) + (lane&15))*H_ + j0 + ((lane>>4)<<3)) = v;
    }
    WAITVM(0);
    if (lane == 0)
      __hip_atomic_store(&fH[wg*4+bg], (unsigned)(t+1), __ATOMIC_RELAXED, __HIP_MEMORY_SCOPE_AGENT);
  }
#undef ISSUE8
#undef CONS1
#undef CONS2
}

// ---------------- launch ----------------
extern "C" void kernel_launch(void* const* d_in, const int* in_sizes, int n_in,
                              void* d_out, int out_size, void* d_ws, size_t ws_size,
                              hipStream_t stream)
{
  const int*   X    = (const int*)  d_in[0];
  const float* h0   = (const float*)d_in[1];
  const float* emb  = (const float*)d_in[2];
  const float* Wzh  = (const float*)d_in[3];
  const float* bzh  = (const float*)d_in[4];
  const float* Wzx  = (const float*)d_in[5];
  const float* bzx  = (const float*)d_in[6];
  const float* Wrh  = (const float*)d_in[7];
  const float* brh  = (const float*)d_in[8];
  const float* Wrx  = (const float*)d_in[9];
  const float* brx  = (const float*)d_in[10];
  const float* Wuh  = (const float*)d_in[11];
  const float* buh  = (const float*)d_in[12];
  const float* Wux  = (const float*)d_in[13];
  const float* bux  = (const float*)d_in[14];
  const float* Wxh  = (const float*)d_in[15];
  const float* bxh  = (const float*)d_in[16];
  const float* Wc   = (const float*)d_in[17];
  const float* bc   = (const float*)d_in[18];
  (void)in_sizes; (void)n_in;

  char* ws = (char*)d_ws;
  if (ws_size < WS_NEED){
    (void)hipMemsetAsync(d_out, 0, (size_t)out_size*4, stream);  // visible failure
    return;
  }

  (void)hipMemsetAsync(ws + OFF_FH, 0, 2048, stream);   // fH + fR

  k_cvt_embed<<<4096, 256, 0, stream>>>(emb, (unsigned short*)(ws + OFF_EMB));
  k_build_wx <<<1536, 256, 0, stream>>>(Wzx, Wrx, Wux, (unsigned short*)(ws + OFF_WXALL));
  k_biasg    <<<12,   256, 0, stream>>>(bzh, bzx, brh, brx, buh, bux, (float*)(ws + OFF_BIASG));
  k_fragW    <<<2048, 256, 0, stream>>>(Wzh, (unsigned short*)(ws + OFF_WZF));
  k_fragW    <<<2048, 256, 0, stream>>>(Wrh, (unsigned short*)(ws + OFF_WRF));
  k_fragW    <<<2048, 256, 0, stream>>>(Wuh, (unsigned short*)(ws + OFF_WUF));
  k_wcomb    <<<64,   256, 0, stream>>>(Wc, Wxh, (unsigned short*)(ws + OFF_WCOMB));
  k_bcomb    <<<4,    256, 0, stream>>>(Wc, bxh, bc, (float*)(ws + OFF_BCOMB));
  k_hinit    <<<256,  256, 0, stream>>>(h0, (unsigned short*)(ws + OFF_HB));

  // G = gather(embed) @ WxAll^T + bias -> layout [t][gcol][64b] bf16
  gemm_bt<true,2><<<6144, 256, 0, stream>>>(
      nullptr, X, (const unsigned short*)(ws + OFF_EMB),
      (const unsigned short*)(ws + OFF_WXALL), (const float*)(ws + OFF_BIASG),
      (void*)(ws + OFF_G), 512, 8, 24, 3072);

  (void)hipFuncSetAttribute((const void*)k_scan, hipFuncAttributeMaxDynamicSharedMemorySize, 102400);
  k_scan<<<NWG, 256, 102400, stream>>>(h0, ws);

  // out[b,t,c] = Hs @ Wcomb^T + bcomb (scatter rows t*64+b -> b*512+t)
  gemm_bt<false,1><<<2048, 256, 0, stream>>>(
      (const unsigned short*)(ws + OFF_HS), nullptr, nullptr,
      (const unsigned short*)(ws + OFF_WCOMB), (const float*)(ws + OFF_BCOMB),
      d_out, 1024, 16, 8, 1024);
}